// Round 4
// baseline (357.772 us; speedup 1.0000x reference)
//
#include <hip/hip_runtime.h>

// Born-series scattering, fully fused recompute-G approach.
// M=4096 pts, 4 wavenumbers (0.5,1,1.5,2), 5 Born iterations, 64 obs dirs.
// R4: BIT-FAITHFUL D^2. The divergent Born spectrum is set by the closest
// pairs, where the reference's Gram formula cancels catastrophically; output
// tracks the exact fp32 rounding of those entries. Reproduce the reference
// rounding sequence: dot = fma chain over k (x first, acc from rounded x*x),
// d2 = (r2_i + r2_j) - 2*dot with two separate roundings (contract off).
//
// ws layout (floats):
//   colpack[M][12]: x,y,z,r2, ar[4], ai[4]          (a = vw * psi, per k)
//   vw[M]                                            (V*weights)
//   p0r[4][M], p0i[4][M]                            (incident wave)
//   yr[4][M], yi[4][M]                              (matvec accumulators)

#define MM 4096
#define NK 4
#define CGREEN 0.07957747154594767f   // 1/(4*pi)

#define OFF_VW  49152
#define OFF_P0R 53248
#define OFF_P0I 69632
#define OFF_YR  86016
#define OFF_YI  102400

__global__ __launch_bounds__(256) void init_k(const float* __restrict__ V,
                                              const float* __restrict__ pts,
                                              const float* __restrict__ w,
                                              float* __restrict__ ws) {
#pragma clang fp contract(off)
    int i = blockIdx.x * 256 + threadIdx.x;
    float x = pts[3 * i], y = pts[3 * i + 1], z = pts[3 * i + 2];
    float vw = V[i] * w[i];
    // np.sum(pts*pts, axis=1): each square rounded, sequential add, no fma
    float xx = x * x, yy = y * y, zz = z * z;
    float r2 = (xx + yy) + zz;
    float* cp = ws + i * 12;
    cp[0] = x; cp[1] = y; cp[2] = z; cp[3] = r2;
    ws[OFF_VW + i] = vw;
#pragma unroll
    for (int n = 0; n < NK; n++) {
        float kk = 0.5f * (float)(n + 1);
        float s, c;
        sincosf(kk * z, &s, &c);       // dot_d = pts . (0,0,1) = z
        ws[OFF_P0R + n * MM + i] = c;
        ws[OFF_P0I + n * MM + i] = s;
        cp[4 + n] = vw * c;
        cp[8 + n] = vw * s;
        ws[OFF_YR + n * MM + i] = 0.0f;
        ws[OFF_YI + n * MM + i] = 0.0f;
    }
}

__device__ __forceinline__ void body(float rx, float ry, float rz, float rr2,
                                     int rowg, int jg,
                                     float4 A, float4 R, float4 I,
                                     float acc[8]) {
#pragma clang fp contract(off)
    // K=3 sgemm/XLA dot: acc=0; fma over k in order -> round(x*x) then fma y, z.
    float dot = fmaf(rz, A.z, fmaf(ry, A.y, rx * A.x));
    // D2 = (r2_i + r2_j) - 2*dot : two separate roundings, NO fma.
    float r2s = rr2 + A.w;
    float twod = 2.0f * dot;            // exact
    float d2 = r2s - twod;              // single rounded subtract
    d2 = fmaxf(d2, 1e-12f);             // clip(D2, 1e-12)
    float D = sqrtf(d2);                // IEEE sqrt
    float Dc = fmaxf(D, 1e-6f);
    float invD = 1.0f / Dc;             // IEEE div
    float scale = (rowg == jg) ? 0.0f : (CGREEN * invD);
    float s1, c1;
    sincosf(0.5f * D, &s1, &c1);        // k=0.5 base angle (0.5*D exact)
    float c2 = fmaf(c1, c1, -s1 * s1);  // cos(1.0 D)
    float s2 = 2.0f * c1 * s1;
    float c3 = fmaf(c2, c1, -s2 * s1);  // cos(1.5 D)
    float s3 = fmaf(s2, c1,  c2 * s1);
    float c4 = fmaf(c2, c2, -s2 * s2);  // cos(2.0 D)
    float s4 = 2.0f * c2 * s2;
    // y_r += scale*(c*ar - s*ai); y_i += scale*(c*ai + s*ar)
    acc[0] = fmaf(scale, fmaf(c1, R.x, -s1 * I.x), acc[0]);
    acc[1] = fmaf(scale, fmaf(c1, I.x,  s1 * R.x), acc[1]);
    acc[2] = fmaf(scale, fmaf(c2, R.y, -s2 * I.y), acc[2]);
    acc[3] = fmaf(scale, fmaf(c2, I.y,  s2 * R.y), acc[3]);
    acc[4] = fmaf(scale, fmaf(c3, R.z, -s3 * I.z), acc[4]);
    acc[5] = fmaf(scale, fmaf(c3, I.z,  s3 * R.z), acc[5]);
    acc[6] = fmaf(scale, fmaf(c4, R.w, -s4 * I.w), acc[6]);
    acc[7] = fmaf(scale, fmaf(c4, I.w,  s4 * R.w), acc[7]);
}

// grid: (64 col-chunks, 8 row-groups); block 256; 2 rows/thread.
__global__ __launch_bounds__(256) void matvec_k(float* __restrict__ ws) {
    __shared__ __align__(16) float tile[64 * 12];
    const int chunk = blockIdx.x;
    const int rg = blockIdx.y;
    for (int idx = threadIdx.x; idx < 768; idx += 256)
        tile[idx] = ws[chunk * 768 + idx];
    __syncthreads();
    const int r0 = rg * 512 + threadIdx.x;
    const int r1 = r0 + 256;
    const float4 row0 = *(const float4*)&ws[r0 * 12];   // x,y,z,r2
    const float4 row1 = *(const float4*)&ws[r1 * 12];
    float a0[8], a1[8];
#pragma unroll
    for (int i = 0; i < 8; i++) { a0[i] = 0.0f; a1[i] = 0.0f; }
    const int jg0 = chunk * 64;
#pragma unroll 2
    for (int j = 0; j < 64; j++) {
        const float4* cp = (const float4*)&tile[j * 12];
        float4 A = cp[0], R = cp[1], I = cp[2];   // same addr all lanes: LDS broadcast
        body(row0.x, row0.y, row0.z, row0.w, r0, jg0 + j, A, R, I, a0);
        body(row1.x, row1.y, row1.z, row1.w, r1, jg0 + j, A, R, I, a1);
    }
    float* yr = ws + OFF_YR;
    float* yi = ws + OFF_YI;
#pragma unroll
    for (int n = 0; n < NK; n++) {
        atomicAdd(&yr[n * MM + r0], a0[2 * n]);
        atomicAdd(&yi[n * MM + r0], a0[2 * n + 1]);
        atomicAdd(&yr[n * MM + r1], a1[2 * n]);
        atomicAdd(&yi[n * MM + r1], a1[2 * n + 1]);
    }
}

__global__ __launch_bounds__(256) void update_k(float* __restrict__ ws) {
    int i = blockIdx.x * 256 + threadIdx.x;
    float vw = ws[OFF_VW + i];
#pragma unroll
    for (int n = 0; n < NK; n++) {
        float pr = ws[OFF_P0R + n * MM + i] + ws[OFF_YR + n * MM + i];
        float pi = ws[OFF_P0I + n * MM + i] + ws[OFF_YI + n * MM + i];
        ws[i * 12 + 4 + n] = vw * pr;
        ws[i * 12 + 8 + n] = vw * pi;
        ws[OFF_YR + n * MM + i] = 0.0f;
        ws[OFF_YI + n * MM + i] = 0.0f;
    }
}

// one block per (k, obs_dir) pair: 256 blocks
__global__ __launch_bounds__(256) void far_k(const float* __restrict__ obs,
                                             const float* __restrict__ ws,
                                             float* __restrict__ out) {
    int kidx = blockIdx.x >> 6;
    int d = blockIdx.x & 63;
    float kk = 0.5f * (float)(kidx + 1);
    float ox = obs[3 * d], oy = obs[3 * d + 1], oz = obs[3 * d + 2];
    float fr = 0.0f, fi = 0.0f;
    for (int j = threadIdx.x; j < MM; j += 256) {
        const float* c = ws + j * 12;
        // K=3 dot, x-first fma chain (matches refs)
        float q = fmaf(c[2], oz, fmaf(c[1], oy, c[0] * ox));
        float ar = c[4 + kidx], ai = c[8 + kidx];
        float s, co;
        sincosf(kk * q, &s, &co);
        // phr = cos(kq), phi = -sin(kq); ir = ar*phr - ai*phi; ii = ar*phi + ai*phr
        fr += fmaf(ar, co,  ai * s);
        fi += fmaf(ai, co, -ar * s);
    }
#pragma unroll
    for (int off = 32; off > 0; off >>= 1) {
        fr += __shfl_down(fr, off);
        fi += __shfl_down(fi, off);
    }
    __shared__ float red[4][2];
    int wave = threadIdx.x >> 6;
    if ((threadIdx.x & 63) == 0) { red[wave][0] = fr; red[wave][1] = fi; }
    __syncthreads();
    if (threadIdx.x == 0) {
        fr = red[0][0] + red[1][0] + red[2][0] + red[3][0];
        fi = red[0][1] + red[1][1] + red[2][1] + red[3][1];
        out[(kidx * 64 + d) * 2 + 0] = -CGREEN * fr;
        out[(kidx * 64 + d) * 2 + 1] = -CGREEN * fi;
    }
}

extern "C" void kernel_launch(void* const* d_in, const int* in_sizes, int n_in,
                              void* d_out, int out_size, void* d_ws, size_t ws_size,
                              hipStream_t stream) {
    const float* V   = (const float*)d_in[0];
    const float* obs = (const float*)d_in[1];
    const float* pts = (const float*)d_in[2];
    const float* w   = (const float*)d_in[3];
    float* ws  = (float*)d_ws;
    float* out = (float*)d_out;

    init_k<<<16, 256, 0, stream>>>(V, pts, w, ws);
    for (int it = 0; it < 5; it++) {
        matvec_k<<<dim3(64, 8), 256, 0, stream>>>(ws);
        update_k<<<16, 256, 0, stream>>>(ws);
    }
    far_k<<<256, 256, 0, stream>>>(obs, ws, out);
}

// Round 5
// 269.286 us; speedup vs baseline: 1.3286x; 1.3286x over previous
//
#include <hip/hip_runtime.h>

// Born-series scattering, fully fused recompute-G approach.
// M=4096 pts, 4 wavenumbers (0.5,1,1.5,2), 5 Born iterations, 64 obs dirs.
// R4: bit-faithful D^2 (Gram formula rounding sequence) -> absmax 0.0, passed.
// R5: fast-math everything EXCEPT the D^2 rounding sequence:
//   - invD = rsqrtf(d2), D = d2*invD  (kills IEEE div + sqrt; R1==R2 proved
//     trig/rsqrt precision is invisible in the bf16-bucketed output)
//   - __sincosf (native v_sin/v_cos) in the body and far-field
//   - grid 1024 blocks (128 col-chunks x 8 row-groups) = 4 blocks/CU for
//     occupancy 17% -> ~40%, hiding quarter-rate transcendental latency.
//
// ws layout (floats):
//   colpack[M][12]: x,y,z,r2, ar[4], ai[4]          (a = vw * psi, per k)
//   vw[M]                                            (V*weights)
//   p0r[4][M], p0i[4][M]                            (incident wave)
//   yr[4][M], yi[4][M]                              (matvec accumulators)

#define MM 4096
#define NK 4
#define CGREEN 0.07957747154594767f   // 1/(4*pi)

#define OFF_VW  49152
#define OFF_P0R 53248
#define OFF_P0I 69632
#define OFF_YR  86016
#define OFF_YI  102400

__global__ __launch_bounds__(256) void init_k(const float* __restrict__ V,
                                              const float* __restrict__ pts,
                                              const float* __restrict__ w,
                                              float* __restrict__ ws) {
#pragma clang fp contract(off)
    int i = blockIdx.x * 256 + threadIdx.x;
    float x = pts[3 * i], y = pts[3 * i + 1], z = pts[3 * i + 2];
    float vw = V[i] * w[i];
    // np.sum(pts*pts, axis=1): each square rounded, sequential add, no fma
    float xx = x * x, yy = y * y, zz = z * z;
    float r2 = (xx + yy) + zz;
    float* cp = ws + i * 12;
    cp[0] = x; cp[1] = y; cp[2] = z; cp[3] = r2;
    ws[OFF_VW + i] = vw;
#pragma unroll
    for (int n = 0; n < NK; n++) {
        float kk = 0.5f * (float)(n + 1);
        float s, c;
        sincosf(kk * z, &s, &c);       // precise: p0 error amplifies through series
        ws[OFF_P0R + n * MM + i] = c;
        ws[OFF_P0I + n * MM + i] = s;
        cp[4 + n] = vw * c;
        cp[8 + n] = vw * s;
        ws[OFF_YR + n * MM + i] = 0.0f;
        ws[OFF_YI + n * MM + i] = 0.0f;
    }
}

__device__ __forceinline__ void body(float rx, float ry, float rz, float rr2,
                                     int rowg, int jg,
                                     float4 A, float4 R, float4 I,
                                     float acc[8]) {
    // ---- bit-faithful D^2 (DO NOT TOUCH: sets the Born spectrum) ----
    float d2;
    {
#pragma clang fp contract(off)
        // K=3 sgemm/XLA dot: acc=0; fma over k in order, x*x rounded first.
        float dot = fmaf(rz, A.z, fmaf(ry, A.y, rx * A.x));
        float r2s = rr2 + A.w;          // rounded add
        float twod = 2.0f * dot;        // exact
        d2 = r2s - twod;                // single rounded subtract, NO fma
    }
    d2 = fmaxf(d2, 1e-12f);             // clip(D2, 1e-12)
    // ---- fast-math from here (proven invisible in bucketed output) ----
    float invD = __frsqrt_rn(d2) ;      // ~= 1/sqrt(d2); d2>=1e-12 -> invD<=1e6
    float D = d2 * invD;                // sqrt(d2)
    float scale = (rowg == jg) ? 0.0f : (CGREEN * invD);
    float s1, c1;
    __sincosf(0.5f * D, &s1, &c1);      // native v_sin/v_cos
    float c2 = fmaf(c1, c1, -s1 * s1);  // cos(1.0 D)
    float s2 = 2.0f * c1 * s1;
    float c3 = fmaf(c2, c1, -s2 * s1);  // cos(1.5 D)
    float s3 = fmaf(s2, c1,  c2 * s1);
    float c4 = fmaf(c2, c2, -s2 * s2);  // cos(2.0 D)
    float s4 = 2.0f * c2 * s2;
    // y_r += scale*(c*ar - s*ai); y_i += scale*(c*ai + s*ar)
    acc[0] = fmaf(scale, fmaf(c1, R.x, -s1 * I.x), acc[0]);
    acc[1] = fmaf(scale, fmaf(c1, I.x,  s1 * R.x), acc[1]);
    acc[2] = fmaf(scale, fmaf(c2, R.y, -s2 * I.y), acc[2]);
    acc[3] = fmaf(scale, fmaf(c2, I.y,  s2 * R.y), acc[3]);
    acc[4] = fmaf(scale, fmaf(c3, R.z, -s3 * I.z), acc[4]);
    acc[5] = fmaf(scale, fmaf(c3, I.z,  s3 * R.z), acc[5]);
    acc[6] = fmaf(scale, fmaf(c4, R.w, -s4 * I.w), acc[6]);
    acc[7] = fmaf(scale, fmaf(c4, I.w,  s4 * R.w), acc[7]);
}

// grid: (128 col-chunks of 32, 8 row-groups of 512); block 256; 2 rows/thread.
__global__ __launch_bounds__(256) void matvec_k(float* __restrict__ ws) {
    __shared__ __align__(16) float tile[32 * 12];
    const int chunk = blockIdx.x;
    const int rg = blockIdx.y;
    if (threadIdx.x < 96) {
        ((float4*)tile)[threadIdx.x] = ((const float4*)(ws + chunk * 384))[threadIdx.x];
    }
    __syncthreads();
    const int r0 = rg * 512 + threadIdx.x;
    const int r1 = r0 + 256;
    const float4 row0 = *(const float4*)&ws[r0 * 12];   // x,y,z,r2
    const float4 row1 = *(const float4*)&ws[r1 * 12];
    float a0[8], a1[8];
#pragma unroll
    for (int i = 0; i < 8; i++) { a0[i] = 0.0f; a1[i] = 0.0f; }
    const int jg0 = chunk * 32;
#pragma unroll 2
    for (int j = 0; j < 32; j++) {
        const float4* cp = (const float4*)&tile[j * 12];
        float4 A = cp[0], R = cp[1], I = cp[2];   // same addr all lanes: LDS broadcast
        body(row0.x, row0.y, row0.z, row0.w, r0, jg0 + j, A, R, I, a0);
        body(row1.x, row1.y, row1.z, row1.w, r1, jg0 + j, A, R, I, a1);
    }
    float* yr = ws + OFF_YR;
    float* yi = ws + OFF_YI;
#pragma unroll
    for (int n = 0; n < NK; n++) {
        atomicAdd(&yr[n * MM + r0], a0[2 * n]);
        atomicAdd(&yi[n * MM + r0], a0[2 * n + 1]);
        atomicAdd(&yr[n * MM + r1], a1[2 * n]);
        atomicAdd(&yi[n * MM + r1], a1[2 * n + 1]);
    }
}

__global__ __launch_bounds__(256) void update_k(float* __restrict__ ws) {
    int i = blockIdx.x * 256 + threadIdx.x;
    float vw = ws[OFF_VW + i];
#pragma unroll
    for (int n = 0; n < NK; n++) {
        float pr = ws[OFF_P0R + n * MM + i] + ws[OFF_YR + n * MM + i];
        float pi = ws[OFF_P0I + n * MM + i] + ws[OFF_YI + n * MM + i];
        ws[i * 12 + 4 + n] = vw * pr;
        ws[i * 12 + 8 + n] = vw * pi;
        ws[OFF_YR + n * MM + i] = 0.0f;
        ws[OFF_YI + n * MM + i] = 0.0f;
    }
}

// one block per (k, obs_dir) pair: 256 blocks
__global__ __launch_bounds__(256) void far_k(const float* __restrict__ obs,
                                             const float* __restrict__ ws,
                                             float* __restrict__ out) {
    int kidx = blockIdx.x >> 6;
    int d = blockIdx.x & 63;
    float kk = 0.5f * (float)(kidx + 1);
    float ox = obs[3 * d], oy = obs[3 * d + 1], oz = obs[3 * d + 2];
    float fr = 0.0f, fi = 0.0f;
    for (int j = threadIdx.x; j < MM; j += 256) {
        const float* c = ws + j * 12;
        float q = fmaf(c[2], oz, fmaf(c[1], oy, c[0] * ox));
        float ar = c[4 + kidx], ai = c[8 + kidx];
        float s, co;
        __sincosf(kk * q, &s, &co);
        // phr = cos(kq), phi = -sin(kq); ir = ar*phr - ai*phi; ii = ar*phi + ai*phr
        fr += fmaf(ar, co,  ai * s);
        fi += fmaf(ai, co, -ar * s);
    }
#pragma unroll
    for (int off = 32; off > 0; off >>= 1) {
        fr += __shfl_down(fr, off);
        fi += __shfl_down(fi, off);
    }
    __shared__ float red[4][2];
    int wave = threadIdx.x >> 6;
    if ((threadIdx.x & 63) == 0) { red[wave][0] = fr; red[wave][1] = fi; }
    __syncthreads();
    if (threadIdx.x == 0) {
        fr = red[0][0] + red[1][0] + red[2][0] + red[3][0];
        fi = red[0][1] + red[1][1] + red[2][1] + red[3][1];
        out[(kidx * 64 + d) * 2 + 0] = -CGREEN * fr;
        out[(kidx * 64 + d) * 2 + 1] = -CGREEN * fi;
    }
}

extern "C" void kernel_launch(void* const* d_in, const int* in_sizes, int n_in,
                              void* d_out, int out_size, void* d_ws, size_t ws_size,
                              hipStream_t stream) {
    const float* V   = (const float*)d_in[0];
    const float* obs = (const float*)d_in[1];
    const float* pts = (const float*)d_in[2];
    const float* w   = (const float*)d_in[3];
    float* ws  = (float*)d_ws;
    float* out = (float*)d_out;

    init_k<<<16, 256, 0, stream>>>(V, pts, w, ws);
    for (int it = 0; it < 5; it++) {
        matvec_k<<<dim3(128, 8), 256, 0, stream>>>(ws);
        update_k<<<16, 256, 0, stream>>>(ws);
    }
    far_k<<<256, 256, 0, stream>>>(obs, ws, out);
}